// Round 1
// baseline (154.067 us; speedup 1.0000x reference)
//
#include <hip/hip_runtime.h>

#define NF 16
#define NH 32
#define JC 8

__device__ __forceinline__ float fast_sigmoid(float v) {
    // rcp(1+exp(-v)); saturates correctly: v->+inf => 1, v->-inf => 0
    float e = __expf(-v);
    return __builtin_amdgcn_rcpf(1.0f + e);
}

__device__ __forceinline__ float fast_tanh(float v) {
    // 1 - 2/(1+exp(2v)); v->+inf => 1, v->-inf => -1
    float e = __expf(2.0f * v);
    return 1.0f - 2.0f * __builtin_amdgcn_rcpf(1.0f + e);
}

__global__ __launch_bounds__(256) void gconv_lstm_kernel(
    const float* __restrict__ x,
    const float* __restrict__ hin,
    const float* __restrict__ cin,
    const float* __restrict__ Wx,   // [4,16,32]
    const float* __restrict__ bx,   // [4,32]
    const float* __restrict__ Wh,   // [4,32,32]
    const float* __restrict__ bh,   // [4,32]
    const float* __restrict__ wc,   // [3,32]
    const float* __restrict__ bg,   // [4,32]
    const float* __restrict__ Wlin, // [32,1]
    const float* __restrict__ blin, // [1]
    float* __restrict__ out,        // [N]
    float* __restrict__ h0_out,     // [N,32]
    float* __restrict__ c_out,      // [N,32]
    int N)
{
    int n = blockIdx.x * blockDim.x + threadIdx.x;
    if (n >= N) return;

    // ---- load x row (16 floats, 4x float4) ----
    float xv[NF];
    {
        const float4* p = reinterpret_cast<const float4*>(x + (size_t)n * NF);
        #pragma unroll
        for (int i = 0; i < NF / 4; ++i) {
            float4 v = p[i];
            xv[4*i+0] = v.x; xv[4*i+1] = v.y; xv[4*i+2] = v.z; xv[4*i+3] = v.w;
        }
    }

    // ---- load h row (32 floats, 8x float4) ----
    float hv[NH];
    {
        const float4* p = reinterpret_cast<const float4*>(hin + (size_t)n * NH);
        #pragma unroll
        for (int i = 0; i < NH / 4; ++i) {
            float4 v = p[i];
            hv[4*i+0] = v.x; hv[4*i+1] = v.y; hv[4*i+2] = v.z; hv[4*i+3] = v.w;
        }
    }

    float outacc = 0.0f;

    // j0 loop kept as a real loop (4 iterations) to bound code size.
    #pragma unroll 1
    for (int j0 = 0; j0 < NH; j0 += JC) {
        float acc0[JC], acc1[JC], acc2[JC], acc3[JC];

        // init with combined biases (b_x + b_h + b_g) -- all wave-uniform scalar loads
        #pragma unroll
        for (int jj = 0; jj < JC; ++jj) {
            int j = j0 + jj;
            acc0[jj] = bx[0*NH + j] + bh[0*NH + j] + bg[0*NH + j];
            acc1[jj] = bx[1*NH + j] + bh[1*NH + j] + bg[1*NH + j];
            acc2[jj] = bx[2*NH + j] + bh[2*NH + j] + bg[2*NH + j];
            acc3[jj] = bx[3*NH + j] + bh[3*NH + j] + bg[3*NH + j];
        }

        // x @ W_x  (weights are uniform-indexed -> SGPR operands on the FMAs)
        #pragma unroll
        for (int f = 0; f < NF; ++f) {
            float xf = xv[f];
            #pragma unroll
            for (int jj = 0; jj < JC; ++jj) {
                int j = j0 + jj;
                acc0[jj] = fmaf(xf, Wx[(0*NF + f)*NH + j], acc0[jj]);
                acc1[jj] = fmaf(xf, Wx[(1*NF + f)*NH + j], acc1[jj]);
                acc2[jj] = fmaf(xf, Wx[(2*NF + f)*NH + j], acc2[jj]);
                acc3[jj] = fmaf(xf, Wx[(3*NF + f)*NH + j], acc3[jj]);
            }
        }

        // h @ W_h
        #pragma unroll
        for (int k = 0; k < NH; ++k) {
            float hk = hv[k];
            #pragma unroll
            for (int jj = 0; jj < JC; ++jj) {
                int j = j0 + jj;
                acc0[jj] = fmaf(hk, Wh[(0*NH + k)*NH + j], acc0[jj]);
                acc1[jj] = fmaf(hk, Wh[(1*NH + k)*NH + j], acc1[jj]);
                acc2[jj] = fmaf(hk, Wh[(2*NH + k)*NH + j], acc2[jj]);
                acc3[jj] = fmaf(hk, Wh[(3*NH + k)*NH + j], acc3[jj]);
            }
        }

        // ---- load c chunk ----
        float cv[JC];
        {
            const float4* p = reinterpret_cast<const float4*>(cin + (size_t)n * NH + j0);
            #pragma unroll
            for (int i = 0; i < JC / 4; ++i) {
                float4 v = p[i];
                cv[4*i+0] = v.x; cv[4*i+1] = v.y; cv[4*i+2] = v.z; cv[4*i+3] = v.w;
            }
        }

        // ---- gates / state update ----
        float h0v[JC], cnv[JC];
        #pragma unroll
        for (int jj = 0; jj < JC; ++jj) {
            int j = j0 + jj;
            float ci = cv[jj];
            float ig = fast_sigmoid(fmaf(wc[0*NH + j], ci, acc0[jj]));
            float fg = fast_sigmoid(fmaf(wc[1*NH + j], ci, acc1[jj]));
            float tg = fast_tanh(acc2[jj]);
            float cn = fg * ci + ig * tg;
            float og = fast_sigmoid(fmaf(wc[2*NH + j], cn, acc3[jj]));
            float hh = og * fast_tanh(cn);
            cnv[jj] = cn;
            h0v[jj] = hh;
            outacc = fmaf(fmaxf(hh, 0.0f), Wlin[j], outacc);
        }

        // ---- store h0 and c_new chunks (float4) ----
        {
            float4* hp = reinterpret_cast<float4*>(h0_out + (size_t)n * NH + j0);
            hp[0] = make_float4(h0v[0], h0v[1], h0v[2], h0v[3]);
            hp[1] = make_float4(h0v[4], h0v[5], h0v[6], h0v[7]);
            float4* cp = reinterpret_cast<float4*>(c_out + (size_t)n * NH + j0);
            cp[0] = make_float4(cnv[0], cnv[1], cnv[2], cnv[3]);
            cp[1] = make_float4(cnv[4], cnv[5], cnv[6], cnv[7]);
        }
    }

    out[n] = outacc + blin[0];
}

extern "C" void kernel_launch(void* const* d_in, const int* in_sizes, int n_in,
                              void* d_out, int out_size, void* d_ws, size_t ws_size,
                              hipStream_t stream) {
    const float* x    = (const float*)d_in[0];
    // d_in[1] = edge_index (unused, K=1 ChebConv), d_in[2] = edge_weight (unused)
    const float* h    = (const float*)d_in[3];
    const float* c    = (const float*)d_in[4];
    const float* Wx   = (const float*)d_in[5];
    const float* bx   = (const float*)d_in[6];
    const float* Wh   = (const float*)d_in[7];
    const float* bh   = (const float*)d_in[8];
    const float* wc   = (const float*)d_in[9];
    const float* bg   = (const float*)d_in[10];
    const float* Wlin = (const float*)d_in[11];
    const float* blin = (const float*)d_in[12];

    const int N = in_sizes[0] / NF;  // 500000

    float* out  = (float*)d_out;              // [N,1]
    float* h0o  = out + N;                    // [N,32]
    float* co   = h0o + (size_t)N * NH;       // [N,32]

    const int block = 256;
    const int grid = (N + block - 1) / block;
    gconv_lstm_kernel<<<grid, block, 0, stream>>>(
        x, h, c, Wx, bx, Wh, bh, wc, bg, Wlin, blin, out, h0o, co, N);
}

// Round 2
// 74.159 us; speedup vs baseline: 2.0775x; 2.0775x over previous
//
#include <hip/hip_runtime.h>
#include <hip/hip_bf16.h>

#define NF 16
#define NH 32

typedef short bf16x8 __attribute__((ext_vector_type(8)));
typedef float f32x16 __attribute__((ext_vector_type(16)));

__device__ __forceinline__ short f2bf(float f) {
    __hip_bfloat16 b = __float2bfloat16(f);  // RNE
    return *reinterpret_cast<short*>(&b);
}

__device__ __forceinline__ bf16x8 cvt8(float4 a, float4 b) {
    bf16x8 r;
    r[0] = f2bf(a.x); r[1] = f2bf(a.y); r[2] = f2bf(a.z); r[3] = f2bf(a.w);
    r[4] = f2bf(b.x); r[5] = f2bf(b.y); r[6] = f2bf(b.z); r[7] = f2bf(b.w);
    return r;
}

__device__ __forceinline__ float fast_sigmoid(float v) {
    float e = __expf(-v);
    return __builtin_amdgcn_rcpf(1.0f + e);
}

__device__ __forceinline__ float fast_tanh(float v) {
    float e = __expf(2.0f * v);
    return 1.0f - 2.0f * __builtin_amdgcn_rcpf(1.0f + e);
}

// ---------------------------------------------------------------------------
// Prep: pack W = [Wx;Wh] (48x32 per gate) into per-lane MFMA B fragments
// (bf16), and fold the three bias vectors into one.
// B layout for v_mfma_f32_32x32x16_bf16: lane l holds col (l&31),
// k = (l>>5)*8 + e, e=0..7 (8 consecutive k). kstep ks covers global
// k = ks*16 .. ks*16+15, where global k 0..15 = Wx rows, 16..47 = Wh rows.
// Bpack index: (((g*3)+ks)*64 + l)*8 + e   -> 4*3*64*8 shorts = 24576 B.
// bsum: 4*32 floats at byte offset 24576.
// ---------------------------------------------------------------------------
__global__ void prep_kernel(const float* __restrict__ Wx, const float* __restrict__ Wh,
                            const float* __restrict__ bx, const float* __restrict__ bh,
                            const float* __restrict__ bg,
                            short* __restrict__ Bpack, float* __restrict__ bsum)
{
    int t = blockIdx.x * blockDim.x + threadIdx.x;
    if (t < 4 * 3 * 64) {
        int g  = t / 192;
        int ks = (t % 192) / 64;
        int l  = t % 64;
        int col  = l & 31;
        int half = l >> 5;
        #pragma unroll
        for (int e = 0; e < 8; ++e) {
            int gk = ks * 16 + half * 8 + e;
            float w = (gk < NF) ? Wx[(g * NF + gk) * NH + col]
                                : Wh[(g * NH + (gk - NF)) * NH + col];
            Bpack[t * 8 + e] = f2bf(w);
        }
    }
    if (t < 4 * NH) {
        bsum[t] = bx[t] + bh[t] + bg[t];
    }
}

// ---------------------------------------------------------------------------
// Main: one wave = 32 nodes. Gate pre-activations via 12x
// v_mfma_f32_32x32x16_bf16 (4 gates x 3 k-steps, K=48 = x(16)+h(32)).
// A layout: lane l holds row (l&31) [= node], k=(l>>5)*8+e.
// C/D layout: col = lane&31 [= j], row = (reg&3)+8*(reg>>2)+4*(lane>>5) [= node].
// ---------------------------------------------------------------------------
__global__ __launch_bounds__(256) void lstm_mfma_kernel(
    const float* __restrict__ x,
    const float* __restrict__ hin,
    const float* __restrict__ cin,
    const float* __restrict__ wc,    // [3,32]
    const float* __restrict__ Wlin,  // [32]
    const float* __restrict__ blin,  // [1]
    const short* __restrict__ Bpack,
    const float* __restrict__ bsum,
    float* __restrict__ out,
    float* __restrict__ h0o,
    float* __restrict__ co,
    int N)
{
    const int lane = threadIdx.x & 63;
    const int wave = threadIdx.x >> 6;
    const long nb = ((long)blockIdx.x * 4 + wave) * 32;
    if (nb >= N) return;

    const int col  = lane & 31;   // j (hidden index) and A-row (node) selector
    const int half = lane >> 5;

    // ---- A fragments: rows of [x | h] for node nb+col, bf16 ----
    bf16x8 a0, a1, a2;
    {
        const size_t node = (size_t)(nb + col);
        const float* px  = x   + node * NF + half * 8;
        const float* ph  = hin + node * NH + half * 8;
        const float* ph2 = ph + 16;
        a0 = cvt8(*(const float4*)px,  *(const float4*)(px + 4));   // k 0..15  = x
        a1 = cvt8(*(const float4*)ph,  *(const float4*)(ph + 4));   // k 16..31 = h[0..15]
        a2 = cvt8(*(const float4*)ph2, *(const float4*)(ph2 + 4));  // k 32..47 = h[16..31]
    }

    // ---- B fragments (L1-resident after first wave) ----
    bf16x8 bf_[4][3];
    #pragma unroll
    for (int g = 0; g < 4; ++g)
        #pragma unroll
        for (int ks = 0; ks < 3; ++ks)
            bf_[g][ks] = *(const bf16x8*)(Bpack + (((g * 3) + ks) * 64 + lane) * 8);

    // ---- prefetch c for this wave's 16 (node,j) elements per lane ----
    float cv[16];
    #pragma unroll
    for (int r = 0; r < 16; ++r) {
        int nrow = (r & 3) + 8 * (r >> 2) + 4 * half;
        cv[r] = cin[(size_t)(nb + nrow) * NH + col];
    }

    // ---- per-j parameters (uniform within 16-lane groups; L1-cached) ----
    const float wc0 = wc[0 * NH + col];
    const float wc1 = wc[1 * NH + col];
    const float wc2 = wc[2 * NH + col];
    const float wl  = Wlin[col];
    const float bl  = blin[0];

    // ---- accumulators init = folded bias (b_x + b_h + b_g), per gate/col ----
    f32x16 acc[4];
    #pragma unroll
    for (int g = 0; g < 4; ++g) {
        float b = bsum[g * NH + col];
        #pragma unroll
        for (int r = 0; r < 16; ++r) acc[g][r] = b;
    }

    // ---- 12 MFMAs: 4 gates x K=48 ----
    #pragma unroll
    for (int g = 0; g < 4; ++g) {
        acc[g] = __builtin_amdgcn_mfma_f32_32x32x16_bf16(a0, bf_[g][0], acc[g], 0, 0, 0);
        acc[g] = __builtin_amdgcn_mfma_f32_32x32x16_bf16(a1, bf_[g][1], acc[g], 0, 0, 0);
        acc[g] = __builtin_amdgcn_mfma_f32_32x32x16_bf16(a2, bf_[g][2], acc[g], 0, 0, 0);
    }

    // ---- epilogue: gates, state update, stores, out-reduction ----
    #pragma unroll
    for (int r = 0; r < 16; ++r) {
        const int nrow = (r & 3) + 8 * (r >> 2) + 4 * half;
        const size_t node = (size_t)(nb + nrow);
        const size_t off  = node * NH + col;

        const float ci = cv[r];
        const float ig = fast_sigmoid(fmaf(wc0, ci, acc[0][r]));
        const float fg = fast_sigmoid(fmaf(wc1, ci, acc[1][r]));
        const float tg = fast_tanh(acc[2][r]);
        const float cn = fg * ci + ig * tg;
        const float og = fast_sigmoid(fmaf(wc2, cn, acc[3][r]));
        const float hh = og * fast_tanh(cn);

        co[off]  = cn;
        h0o[off] = hh;

        // out[node] = sum_j relu(hh)*Wlin[j] + blin; reduce across the 32
        // lanes of this half (xor masks < 32 stay within the half).
        float p = fmaxf(hh, 0.0f) * wl;
        #pragma unroll
        for (int m = 1; m < 32; m <<= 1) p += __shfl_xor(p, m, 64);
        if (col == 0) out[node] = p + bl;
    }
}

extern "C" void kernel_launch(void* const* d_in, const int* in_sizes, int n_in,
                              void* d_out, int out_size, void* d_ws, size_t ws_size,
                              hipStream_t stream) {
    const float* x    = (const float*)d_in[0];
    // d_in[1] = edge_index (unused, K=1 ChebConv), d_in[2] = edge_weight (unused)
    const float* h    = (const float*)d_in[3];
    const float* c    = (const float*)d_in[4];
    const float* Wx   = (const float*)d_in[5];
    const float* bx   = (const float*)d_in[6];
    const float* Wh   = (const float*)d_in[7];
    const float* bh   = (const float*)d_in[8];
    const float* wc   = (const float*)d_in[9];
    const float* bg   = (const float*)d_in[10];
    const float* Wlin = (const float*)d_in[11];
    const float* blin = (const float*)d_in[12];

    const int N = in_sizes[0] / NF;  // 500000

    float* out = (float*)d_out;             // [N,1]
    float* h0o = out + N;                   // [N,32]
    float* co  = h0o + (size_t)N * NH;      // [N,32]

    short* Bpack = (short*)d_ws;                           // 24576 B
    float* bsum  = (float*)((char*)d_ws + 4 * 3 * 64 * 8 * sizeof(short));

    prep_kernel<<<3, 256, 0, stream>>>(Wx, Wh, bx, bh, bg, Bpack, bsum);

    const int nodes_per_block = 4 * NH;  // 4 waves x 32 nodes
    const int grid = (N + nodes_per_block - 1) / nodes_per_block;
    lstm_mfma_kernel<<<grid, 256, 0, stream>>>(
        x, h, c, wc, Wlin, blin, Bpack, bsum, out, h0o, co, N);
}